// Round 1
// baseline (4893.288 us; speedup 1.0000x reference)
//
#include <hip/hip_runtime.h>
#include <hip/hip_bf16.h>

// GRU last-hidden: B=64, T=512, I=256, H=512, fp32 in/out.
// Persistent kernel: 64 WGs x 256 thr. WG w owns h-cols [8w,8w+8) for ALL
// batches; its 24 gate rows of W_hh/W_ih live in VGPR MFMA B-fragments for
// the whole kernel. Per step: x-proj MFMAs (h-independent, hoisted before the
// barrier poll), device-scope slot barrier, h-proj MFMAs, gate epilogue.
// fp32 master h state stays in the producer lane's registers; bf16 copy in ws
// is only the MFMA broadcast medium (double-buffered).

#define NB 64
#define NT 512
#define NI 256
#define NH 512

typedef __attribute__((ext_vector_type(8))) short bf16x8;
typedef __attribute__((ext_vector_type(4))) float f32x4;

static __device__ __forceinline__ short f2b(float f) {
  // fp32 -> bf16 bits, round-to-nearest-even (inputs finite)
  unsigned u = __builtin_bit_cast(unsigned, f);
  unsigned r = (u + 0x7fffu + ((u >> 16) & 1u)) >> 16;
  return (short)r;
}
static __device__ __forceinline__ float sigm(float x) {
  return 1.0f / (1.0f + __expf(-x));
}
static __device__ __forceinline__ float tanh_f(float x) {
  // 1 - 2/(e^{2x}+1); saturates cleanly to +/-1, no NaN for finite x
  return 1.0f - 2.0f / (__expf(2.0f * x) + 1.0f);
}

__global__ __launch_bounds__(256, 1)
void gru_persistent(const float* __restrict__ x,
                    const float* __restrict__ Wih,
                    const float* __restrict__ Whh,
                    const float* __restrict__ bih,
                    const float* __restrict__ bhh,
                    float* __restrict__ out,
                    unsigned char* __restrict__ ws) {
  const int wg   = blockIdx.x;    // 0..63 : owns h-cols [8wg, 8wg+8)
  const int tid  = threadIdx.x;   // 0..255
  const int wave = tid >> 6;      // 0..3  : owns batches [16*wave, 16*wave+16)
  const int lane = tid & 63;
  const int c    = lane & 15;     // tile col / A-row index
  const int q    = lane >> 4;     // quad: k-group (A/B), row-group (C/D)

  // ws layout: [0,8K) barrier slots (int, 128B stride); h bufs at 16K and 80K
  // (64x512 bf16 each); x-as-bf16 at 144K (16 MB). Total ~16.9 MB.
  int* slots = (int*)ws;
  unsigned short* hb0 = (unsigned short*)(ws + 16384);
  unsigned short* hb1 = (unsigned short*)(ws + 16384 + 65536);
  unsigned short* xb  = (unsigned short*)(ws + 16384 + 2 * 65536);

  // ---- prologue: x fp32->bf16, zero h0 ----
  {
    const float4* x4 = (const float4*)x;
    const int total4 = NB * NT * NI / 4;   // 2097152
    const int nthr = NB * 256;             // 16384 grid threads
    for (int i = wg * 256 + tid; i < total4; i += nthr) {
      float4 v = x4[i];
      ushort4 o;
      o.x = (unsigned short)f2b(v.x);
      o.y = (unsigned short)f2b(v.y);
      o.z = (unsigned short)f2b(v.z);
      o.w = (unsigned short)f2b(v.w);
      ((ushort4*)xb)[i] = o;
    }
    // h0 = 0: 64x512 bf16 = 16384 dwords, exactly one per grid thread
    ((unsigned int*)hb0)[wg * 256 + tid] = 0u;
  }

  // ---- loop-invariant weight fragments into registers ----
  // B-fragment: lane holds W[n = nt*16 + c][k = kk*32 + q*8 .. +8] as bf16.
  // n_local = gate*8 + jj, gate in {r,z,n}; rows 24..31 zero-padded.
  bf16x8 wh[2][16];  // W_hh, K=512 -> 16 k-steps
  bf16x8 wi[2][8];   // W_ih, K=256 -> 8 k-steps
#pragma unroll
  for (int nt = 0; nt < 2; nt++) {
    int nl = nt * 16 + c;
    bool valid = nl < 24;
    int gate = nl >> 3;
    int jj = nl & 7;
    int grow = valid ? (gate * NH + wg * 8 + jj) : 0;
#pragma unroll
    for (int kk = 0; kk < 16; kk++) {
      const float* p = Whh + (size_t)grow * NH + kk * 32 + q * 8;
      bf16x8 f;
#pragma unroll
      for (int e = 0; e < 8; e++) f[e] = valid ? f2b(p[e]) : (short)0;
      wh[nt][kk] = f;
    }
#pragma unroll
    for (int kk = 0; kk < 8; kk++) {
      const float* p = Wih + (size_t)grow * NI + kk * 32 + q * 8;
      bf16x8 f;
#pragma unroll
      for (int e = 0; e < 8; e++) f[e] = valid ? f2b(p[e]) : (short)0;
      wi[nt][kk] = f;
    }
  }

  // biases for this lane's output column (meaningful for c<8; jj = c&7)
  const int jcol = wg * 8 + (c & 7);
  const float bri = bih[jcol],          brh = bhh[jcol];
  const float bzi = bih[NH + jcol],     bzh = bhh[NH + jcol];
  const float bni = bih[2 * NH + jcol], bnh = bhh[2 * NH + jcol];

  float hold[4] = {0.f, 0.f, 0.f, 0.f};  // fp32 master state (c<8 lanes)

  // ---- barrier round 1: x conversion + h0 visible device-wide ----
  __syncthreads();
  if (tid == 0)
    __hip_atomic_store(&slots[wg * 32], 1, __ATOMIC_RELEASE,
                       __HIP_MEMORY_SCOPE_AGENT);
  if (wave == 0) {
    // 0xAA poison reads as negative int -> signed '< val' poll is safe;
    // '>=' exit tolerates a WG racing one round ahead.
    while (__hip_atomic_load(&slots[lane * 32], __ATOMIC_RELAXED,
                             __HIP_MEMORY_SCOPE_AGENT) < 1)
      __builtin_amdgcn_s_sleep(1);
  }
  __syncthreads();
  __threadfence();  // acquire: invalidate L1/L2 so xb/hb0 reads are fresh

  const int b0 = wave * 16 + c;  // A-fragment batch row for this lane

  for (int t = 0; t < NT; t++) {
    const unsigned short* hcur = (t & 1) ? hb1 : hb0;
    unsigned short* hnext      = (t & 1) ? hb0 : hb1;

    f32x4 aX0 = {0.f, 0.f, 0.f, 0.f}, aX1 = {0.f, 0.f, 0.f, 0.f};
    f32x4 aH0 = {0.f, 0.f, 0.f, 0.f}, aH1 = {0.f, 0.f, 0.f, 0.f};

    // x-projection: independent of h -> before the barrier poll (hides sync)
    const bf16x8* xr = (const bf16x8*)(xb + ((size_t)b0 * NT + t) * NI);
#pragma unroll
    for (int kk = 0; kk < 8; kk++) {
      bf16x8 a = xr[kk * 4 + q];
      aX0 = __builtin_amdgcn_mfma_f32_16x16x32_bf16(a, wi[0][kk], aX0, 0, 0, 0);
      aX1 = __builtin_amdgcn_mfma_f32_16x16x32_bf16(a, wi[1][kk], aX1, 0, 0, 0);
    }

    // wait until every WG has published h_t (value t+1); t=0 covered above
    if (t > 0) {
      if (wave == 0) {
        while (__hip_atomic_load(&slots[lane * 32], __ATOMIC_RELAXED,
                                 __HIP_MEMORY_SCOPE_AGENT) < t + 1)
          __builtin_amdgcn_s_sleep(1);
      }
      __syncthreads();
      __threadfence();  // invalidate stale h lines (buffer reused every 2 steps)
    }

    // h-projection
    const bf16x8* hr = (const bf16x8*)(hcur + (size_t)b0 * NH);
#pragma unroll
    for (int kk = 0; kk < 16; kk++) {
      bf16x8 a = hr[kk * 4 + q];
      aH0 = __builtin_amdgcn_mfma_f32_16x16x32_bf16(a, wh[0][kk], aH0, 0, 0, 0);
      aH1 = __builtin_amdgcn_mfma_f32_16x16x32_bf16(a, wh[1][kk], aH1, 0, 0, 0);
    }

    // epilogue: C/D layout col=lane&15 (n_local), row=q*4+reg (batch).
    // Lane c<8 handles jj=c: r at its own col, z at col c+8 (shfl_xor 8),
    // n in tile1 col c.
#pragma unroll
    for (int r = 0; r < 4; r++) {
      float xz = __shfl_xor(aX0[r], 8, 64);
      float hz = __shfl_xor(aH0[r], 8, 64);
      float rr = sigm(aX0[r] + bri + aH0[r] + brh);
      float zz = sigm(xz + bzi + hz + bzh);
      float nn = tanh_f(aX1[r] + bni + rr * (aH1[r] + bnh));
      float hv = (1.0f - zz) * nn + zz * hold[r];
      hold[r] = hv;
      if (c < 8) {
        int b = wave * 16 + q * 4 + r;
        hnext[(size_t)b * NH + wg * 8 + c] = (unsigned short)f2b(hv);
      }
    }

    // publish h_{t+1}: all waves' stores drained by syncthreads; release
    // store writes back L2 so other XCDs observe the data with the flag.
    __syncthreads();
    if (tid == 0)
      __hip_atomic_store(&slots[wg * 32], t + 2, __ATOMIC_RELEASE,
                         __HIP_MEMORY_SCOPE_AGENT);
  }

  // final h (fp32 master copy) -> d_out
  if (c < 8) {
#pragma unroll
    for (int r = 0; r < 4; r++) {
      int b = wave * 16 + q * 4 + r;
      out[(size_t)b * NH + wg * 8 + c] = hold[r];
    }
  }
}

extern "C" void kernel_launch(void* const* d_in, const int* in_sizes, int n_in,
                              void* d_out, int out_size, void* d_ws, size_t ws_size,
                              hipStream_t stream) {
  const float* x   = (const float*)d_in[0];
  const float* Wih = (const float*)d_in[1];
  const float* Whh = (const float*)d_in[2];
  const float* bih = (const float*)d_in[3];
  const float* bhh = (const float*)d_in[4];
  float* out = (float*)d_out;
  hipLaunchKernelGGL(gru_persistent, dim3(NB), dim3(256), 0, stream,
                     x, Wih, Whh, bih, bhh, out, (unsigned char*)d_ws);
}

// Round 2
// 3538.172 us; speedup vs baseline: 1.3830x; 1.3830x over previous
//
#include <hip/hip_runtime.h>
#include <hip/hip_bf16.h>

// GRU last-hidden: B=64, T=512, I=256, H=512, fp32 in/out.
// Persistent kernel: 64 WGs x 256 thr. WG w owns h-cols [8w,8w+8) for ALL
// batches; its 24 gate rows of W_hh/W_ih live in VGPR MFMA B-fragments for
// the whole kernel.
//
// Round-2 change: per-step sync is now FENCE-FREE. All cross-WG data (h,
// flags) moves via relaxed AGENT-scope atomics whose SC bits make each access
// device-coherent (stores write through past the per-XCD L2; loads force-miss
// L1/L2 to the Infinity Cache). No per-step __threadfence / release fence =>
// no buffer_wbl2/buffer_inv per step, and x/weights stay warm in L1/L2.
// Ordering h-stores -> flag is a per-wave `s_waitcnt vmcnt(0)` + barrier.

#define NB 64
#define NT 512
#define NI 256
#define NH 512

typedef __attribute__((ext_vector_type(8))) short bf16x8;
typedef __attribute__((ext_vector_type(4))) float f32x4;
typedef __attribute__((ext_vector_type(2))) unsigned long long ull2;

static __device__ __forceinline__ short f2b(float f) {
  // fp32 -> bf16 bits, round-to-nearest-even (inputs finite)
  unsigned u = __builtin_bit_cast(unsigned, f);
  unsigned r = (u + 0x7fffu + ((u >> 16) & 1u)) >> 16;
  return (short)r;
}
static __device__ __forceinline__ float sigm(float x) {
  return 1.0f / (1.0f + __expf(-x));
}
static __device__ __forceinline__ float tanh_f(float x) {
  return 1.0f - 2.0f / (__expf(2.0f * x) + 1.0f);
}

__global__ __launch_bounds__(256, 1)
void gru_persistent(const float* __restrict__ x,
                    const float* __restrict__ Wih,
                    const float* __restrict__ Whh,
                    const float* __restrict__ bih,
                    const float* __restrict__ bhh,
                    float* __restrict__ out,
                    unsigned char* __restrict__ ws) {
  const int wg   = blockIdx.x;    // 0..63 : owns h-cols [8wg, 8wg+8)
  const int tid  = threadIdx.x;   // 0..255
  const int wave = tid >> 6;      // 0..3  : owns batches [16*wave, 16*wave+16)
  const int lane = tid & 63;
  const int c    = lane & 15;     // tile col / A-row index
  const int q    = lane >> 4;     // quad: k-group (A/B), row-group (C/D)

  // ws layout: [0,8K) barrier slots (int, 128B stride); h bufs at 16K and 80K
  // (64x512 bf16 each); x-as-bf16 at 144K (16 MB).
  int* slots = (int*)ws;
  unsigned short* hb0 = (unsigned short*)(ws + 16384);
  unsigned short* hb1 = (unsigned short*)(ws + 16384 + 65536);
  unsigned short* xb  = (unsigned short*)(ws + 16384 + 2 * 65536);

  // ---- prologue: x fp32->bf16, zero h0 ----
  {
    const float4* x4 = (const float4*)x;
    const int total4 = NB * NT * NI / 4;
    const int nthr = NB * 256;
    for (int i = wg * 256 + tid; i < total4; i += nthr) {
      float4 v = x4[i];
      ushort4 o;
      o.x = (unsigned short)f2b(v.x);
      o.y = (unsigned short)f2b(v.y);
      o.z = (unsigned short)f2b(v.z);
      o.w = (unsigned short)f2b(v.w);
      ((ushort4*)xb)[i] = o;
    }
    ((unsigned int*)hb0)[wg * 256 + tid] = 0u;
  }

  // ---- loop-invariant weight fragments into registers ----
  bf16x8 wh[2][16];  // W_hh, K=512 -> 16 k-steps
  bf16x8 wi[2][8];   // W_ih, K=256 -> 8 k-steps
#pragma unroll
  for (int nt = 0; nt < 2; nt++) {
    int nl = nt * 16 + c;
    bool valid = nl < 24;
    int gate = nl >> 3;
    int jj = nl & 7;
    int grow = valid ? (gate * NH + wg * 8 + jj) : 0;
#pragma unroll
    for (int kk = 0; kk < 16; kk++) {
      const float* p = Whh + (size_t)grow * NH + kk * 32 + q * 8;
      bf16x8 f;
#pragma unroll
      for (int e = 0; e < 8; e++) f[e] = valid ? f2b(p[e]) : (short)0;
      wh[nt][kk] = f;
    }
#pragma unroll
    for (int kk = 0; kk < 8; kk++) {
      const float* p = Wih + (size_t)grow * NI + kk * 32 + q * 8;
      bf16x8 f;
#pragma unroll
      for (int e = 0; e < 8; e++) f[e] = valid ? f2b(p[e]) : (short)0;
      wi[nt][kk] = f;
    }
  }

  const int jcol = wg * 8 + (c & 7);
  const float bri = bih[jcol],          brh = bhh[jcol];
  const float bzi = bih[NH + jcol],     bzh = bhh[NH + jcol];
  const float bni = bih[2 * NH + jcol], bnh = bhh[2 * NH + jcol];

  float hold[4] = {0.f, 0.f, 0.f, 0.f};  // fp32 master state (c<8 lanes)

  // ---- one-time barrier: x conversion + h0 visible device-wide ----
  // Release store -> wbl2 (flush this XCD's dirty xb/hb0 lines to L3);
  // threadfence after poll -> inv (so cached reads of xb are fresh).
  // This is the ONLY L2 maintenance in the kernel.
  __syncthreads();
  if (tid == 0)
    __hip_atomic_store(&slots[wg * 32], 1, __ATOMIC_RELEASE,
                       __HIP_MEMORY_SCOPE_AGENT);
  if (wave == 0) {
    while (__hip_atomic_load(&slots[lane * 32], __ATOMIC_RELAXED,
                             __HIP_MEMORY_SCOPE_AGENT) < 1)
      __builtin_amdgcn_s_sleep(1);
  }
  __syncthreads();
  __threadfence();

  const int b0 = wave * 16 + c;  // A-fragment batch row for this lane

  for (int t = 0; t < NT; t++) {
    const unsigned short* hcur = (t & 1) ? hb1 : hb0;
    unsigned short* hnext      = (t & 1) ? hb0 : hb1;

    f32x4 aX0 = {0.f, 0.f, 0.f, 0.f}, aX1 = {0.f, 0.f, 0.f, 0.f};
    f32x4 aH0 = {0.f, 0.f, 0.f, 0.f}, aH1 = {0.f, 0.f, 0.f, 0.f};

    const bf16x8* xr = (const bf16x8*)(xb + ((size_t)b0 * NT + t) * NI);

    // x-proj first half: hides flag-arrival latency (cached loads)
#pragma unroll
    for (int kk = 0; kk < 4; kk++) {
      bf16x8 a = xr[kk * 4 + q];
      aX0 = __builtin_amdgcn_mfma_f32_16x16x32_bf16(a, wi[0][kk], aX0, 0, 0, 0);
      aX1 = __builtin_amdgcn_mfma_f32_16x16x32_bf16(a, wi[1][kk], aX1, 0, 0, 0);
    }

    // wait until every WG has published h_t (flag value >= t+1)
    if (t > 0) {
      if (wave == 1) {
        const int need = t + 1;
        while (true) {
          int v = __hip_atomic_load(&slots[lane * 32], __ATOMIC_RELAXED,
                                    __HIP_MEMORY_SCOPE_AGENT);
          if (__all(v >= need)) break;
          __builtin_amdgcn_s_sleep(1);
        }
      }
      __syncthreads();
    }

    // issue h fragment loads: agent-scope relaxed atomics bypass L1/L2
    // (fresh from L3, no fence needed). 16 frags x 2 x 8B per lane.
    const unsigned long long* hp =
        (const unsigned long long*)(hcur + (size_t)b0 * NH);
    bf16x8 hf[16];
#pragma unroll
    for (int kk = 0; kk < 16; kk++) {
      unsigned long long lo = __hip_atomic_load(
          hp + kk * 8 + q * 2, __ATOMIC_RELAXED, __HIP_MEMORY_SCOPE_AGENT);
      unsigned long long hi = __hip_atomic_load(
          hp + kk * 8 + q * 2 + 1, __ATOMIC_RELAXED, __HIP_MEMORY_SCOPE_AGENT);
      ull2 u;
      u[0] = lo;
      u[1] = hi;
      hf[kk] = __builtin_bit_cast(bf16x8, u);
    }

    // x-proj second half: hides h-load L3 latency
#pragma unroll
    for (int kk = 4; kk < 8; kk++) {
      bf16x8 a = xr[kk * 4 + q];
      aX0 = __builtin_amdgcn_mfma_f32_16x16x32_bf16(a, wi[0][kk], aX0, 0, 0, 0);
      aX1 = __builtin_amdgcn_mfma_f32_16x16x32_bf16(a, wi[1][kk], aX1, 0, 0, 0);
    }

    // h-projection
#pragma unroll
    for (int kk = 0; kk < 16; kk++) {
      aH0 = __builtin_amdgcn_mfma_f32_16x16x32_bf16(hf[kk], wh[0][kk], aH0, 0, 0, 0);
      aH1 = __builtin_amdgcn_mfma_f32_16x16x32_bf16(hf[kk], wh[1][kk], aH1, 0, 0, 0);
    }

    // epilogue: C/D layout col=lane&15, row=q*4+reg. Lane c<8 owns col wg*8+c.
#pragma unroll
    for (int r = 0; r < 4; r++) {
      float xz = __shfl_xor(aX0[r], 8, 64);
      float hz = __shfl_xor(aH0[r], 8, 64);
      float rr = sigm(aX0[r] + bri + aH0[r] + brh);
      float zz = sigm(xz + bzi + hz + bzh);
      float nn = tanh_f(aX1[r] + bni + rr * (aH1[r] + bnh));
      float hv = (1.0f - zz) * nn + zz * hold[r];
      hold[r] = hv;
      if (t < NT - 1 && c < 8) {
        int b = wave * 16 + q * 4 + r;
        // write-through to L3 (agent scope): no dirty L2 => no wbl2 needed
        __hip_atomic_store(&hnext[(size_t)b * NH + wg * 8 + c],
                           (unsigned short)f2b(hv), __ATOMIC_RELAXED,
                           __HIP_MEMORY_SCOPE_AGENT);
      }
    }

    if (t < NT - 1) {
      // order: this wave's h stores complete (at L3) ...
      asm volatile("s_waitcnt vmcnt(0)" ::: "memory");
      // ... all waves' stores complete ...
      __syncthreads();
      // ... then publish the flag (write-through, relaxed)
      if (tid == 0)
        __hip_atomic_store(&slots[wg * 32], t + 2, __ATOMIC_RELAXED,
                           __HIP_MEMORY_SCOPE_AGENT);
    }
  }

  // final h (fp32 master copy) -> d_out
  if (c < 8) {
#pragma unroll
    for (int r = 0; r < 4; r++) {
      int b = wave * 16 + q * 4 + r;
      out[(size_t)b * NH + wg * 8 + c] = hold[r];
    }
  }
}

extern "C" void kernel_launch(void* const* d_in, const int* in_sizes, int n_in,
                              void* d_out, int out_size, void* d_ws, size_t ws_size,
                              hipStream_t stream) {
  const float* x   = (const float*)d_in[0];
  const float* Wih = (const float*)d_in[1];
  const float* Whh = (const float*)d_in[2];
  const float* bih = (const float*)d_in[3];
  const float* bhh = (const float*)d_in[4];
  float* out = (float*)d_out;
  hipLaunchKernelGGL(gru_persistent, dim3(NB), dim3(256), 0, stream,
                     x, Wih, Whh, bih, bhh, out, (unsigned char*)d_ws);
}

// Round 3
// 2849.050 us; speedup vs baseline: 1.7175x; 1.2419x over previous
//
#include <hip/hip_runtime.h>
#include <hip/hip_bf16.h>

// GRU last-hidden: B=64, T=512, I=256, H=512, fp32 in/out.
// Persistent kernel: 64 WGs x 256 thr. WG w owns h-cols [8w,8w+8) for ALL
// batches; weights live in VGPR MFMA B-fragments for the whole kernel.
//
// Round-3 structure: barrier-free steady-state loop.
//  - h exchange layout h_ex[wg][batch][8cols] (bf16): producer WG writes a
//    private contiguous 1KB block (coalesced 8B device-coherent stores after
//    a per-wave LDS transpose); consumer fragment = one contiguous 16B pair.
//  - per-step readiness = ONE global counter cnt[t] (monotone, no reset):
//    waves aggregate arrival in LDS, last wave of a WG does one agent-scope
//    atomic add; consumers poll a single address (lanes merge to 1 request).
//  - no __syncthreads in the loop; ordering is per-wave vmcnt(0) + LDS
//    in-order pipeline. All cross-WG data via relaxed agent-scope atomics
//    (write-through past per-XCD L2; loads read L3 directly). No fences.

#define NB 64
#define NT 512
#define NI 256
#define NH 512

typedef __attribute__((ext_vector_type(8))) short bf16x8;
typedef __attribute__((ext_vector_type(4))) float f32x4;
typedef __attribute__((ext_vector_type(2))) unsigned long long ull2;

static __device__ __forceinline__ short f2b(float f) {
  unsigned u = __builtin_bit_cast(unsigned, f);
  unsigned r = (u + 0x7fffu + ((u >> 16) & 1u)) >> 16;
  return (short)r;
}
static __device__ __forceinline__ float sigm(float x) {
  return 1.0f / (1.0f + __expf(-x));
}
static __device__ __forceinline__ float tanh_f(float x) {
  return 1.0f - 2.0f / (__expf(2.0f * x) + 1.0f);
}

__global__ __launch_bounds__(256, 1)
void gru_persistent(const float* __restrict__ x,
                    const float* __restrict__ Wih,
                    const float* __restrict__ Whh,
                    const float* __restrict__ bih,
                    const float* __restrict__ bhh,
                    float* __restrict__ out,
                    unsigned char* __restrict__ ws) {
  const int wg   = blockIdx.x;    // 0..63 : owns h-cols [8wg, 8wg+8)
  const int tid  = threadIdx.x;   // 0..255
  const int wave = tid >> 6;      // 0..3  : owns batches [16*wave, 16*wave+16)
  const int lane = tid & 63;
  const int c    = lane & 15;     // tile col / A-row index
  const int q    = lane >> 4;     // quad: k-group (A/B), row-group (C/D)

  // ws layout: [0,8K) init-barrier slots; [8K,10K) cnt[NT]; h_ex bufs at 16K
  // and 16K+64K (each 64 WG x 64 b x 8 cols x bf16 = 64KB); xb at 16K+128K.
  int* slots = (int*)ws;
  int* cnt = (int*)(ws + 8192);
  unsigned short* hb0 = (unsigned short*)(ws + 16384);
  unsigned short* hb1 = (unsigned short*)(ws + 16384 + 65536);
  unsigned short* xb  = (unsigned short*)(ws + 16384 + 2 * 65536);

  __shared__ unsigned short trans[4][16][8];  // per-wave transpose bounce
  __shared__ int lds_cnt;                     // monotone arrival counter
  if (tid == 0) lds_cnt = 0;

  // ---- prologue: x fp32->bf16, zero h0 and cnt ----
  {
    const float4* x4 = (const float4*)x;
    const int total4 = NB * NT * NI / 4;
    const int nthr = NB * 256;
    for (int i = wg * 256 + tid; i < total4; i += nthr) {
      float4 v = x4[i];
      ushort4 o;
      o.x = (unsigned short)f2b(v.x);
      o.y = (unsigned short)f2b(v.y);
      o.z = (unsigned short)f2b(v.z);
      o.w = (unsigned short)f2b(v.w);
      ((ushort4*)xb)[i] = o;
    }
    ((unsigned int*)hb0)[wg * 256 + tid] = 0u;  // h0 = 0 (64KB total)
    if (wg == 0) { cnt[tid] = 0; cnt[tid + 256] = 0; }
  }

  // ---- loop-invariant weight fragments into registers ----
  bf16x8 wh[2][16];  // W_hh, K=512 -> 16 k-steps
  bf16x8 wi[2][8];   // W_ih, K=256 -> 8 k-steps
#pragma unroll
  for (int nt = 0; nt < 2; nt++) {
    int nl = nt * 16 + c;
    bool valid = nl < 24;
    int gate = nl >> 3;
    int jj = nl & 7;
    int grow = valid ? (gate * NH + wg * 8 + jj) : 0;
#pragma unroll
    for (int kk = 0; kk < 16; kk++) {
      const float* p = Whh + (size_t)grow * NH + kk * 32 + q * 8;
      bf16x8 f;
#pragma unroll
      for (int e = 0; e < 8; e++) f[e] = valid ? f2b(p[e]) : (short)0;
      wh[nt][kk] = f;
    }
#pragma unroll
    for (int kk = 0; kk < 8; kk++) {
      const float* p = Wih + (size_t)grow * NI + kk * 32 + q * 8;
      bf16x8 f;
#pragma unroll
      for (int e = 0; e < 8; e++) f[e] = valid ? f2b(p[e]) : (short)0;
      wi[nt][kk] = f;
    }
  }

  const int jcol = wg * 8 + (c & 7);
  const float bri = bih[jcol],          brh = bhh[jcol];
  const float bzi = bih[NH + jcol],     bzh = bhh[NH + jcol];
  const float bni = bih[2 * NH + jcol], bnh = bhh[2 * NH + jcol];

  float hold[4] = {0.f, 0.f, 0.f, 0.f};  // fp32 master state (c<8 lanes)

  // ---- one-time init barrier: xb, h0, cnt zeros visible device-wide ----
  // (release store -> wbl2 flush; threadfence after poll -> inv). This is
  // the only cache-maintenance in the kernel.
  __syncthreads();
  if (tid == 0)
    __hip_atomic_store(&slots[wg * 32], 1, __ATOMIC_RELEASE,
                       __HIP_MEMORY_SCOPE_AGENT);
  if (wave == 0) {
    while (__hip_atomic_load(&slots[lane * 32], __ATOMIC_RELAXED,
                             __HIP_MEMORY_SCOPE_AGENT) < 1)
      __builtin_amdgcn_s_sleep(1);
  }
  __syncthreads();
  __threadfence();

  const int b0 = wave * 16 + c;  // A-fragment batch row for this lane

  for (int t = 0; t < NT; t++) {
    const unsigned short* hcur = (t & 1) ? hb1 : hb0;
    unsigned short* hnext      = (t & 1) ? hb0 : hb1;

    f32x4 aX0 = {0.f, 0.f, 0.f, 0.f}, aX1 = {0.f, 0.f, 0.f, 0.f};
    f32x4 aH0 = {0.f, 0.f, 0.f, 0.f}, aH1 = {0.f, 0.f, 0.f, 0.f};

    const bf16x8* xr = (const bf16x8*)(xb + ((size_t)b0 * NT + t) * NI);

    // x-proj first half (cached loads; fills time before readiness)
#pragma unroll
    for (int kk = 0; kk < 4; kk++) {
      bf16x8 a = xr[kk * 4 + q];
      aX0 = __builtin_amdgcn_mfma_f32_16x16x32_bf16(a, wi[0][kk], aX0, 0, 0, 0);
      aX1 = __builtin_amdgcn_mfma_f32_16x16x32_bf16(a, wi[1][kk], aX1, 0, 0, 0);
    }

    // wait for h_t: single-address poll (all lanes same addr -> 1 request)
    if (t > 0) {
      while (__hip_atomic_load(&cnt[t - 1], __ATOMIC_RELAXED,
                               __HIP_MEMORY_SCOPE_AGENT) < NB) {
      }
      asm volatile("" ::: "memory");  // compiler barrier only (no HW cost)
    }

    // h fragment loads: h_ex[wg' = kk*4+q][b0][0..8) -> one contiguous 16B
    // pair per kk; 16 lanes (consecutive b0) form 256B coalesced chunks.
    const unsigned long long* hbase = (const unsigned long long*)hcur;
    bf16x8 hf[16];
#pragma unroll
    for (int kk = 0; kk < 16; kk++) {
      size_t idx = ((size_t)(kk * 4 + q) * 64 + b0) * 2;
      unsigned long long lo = __hip_atomic_load(
          hbase + idx, __ATOMIC_RELAXED, __HIP_MEMORY_SCOPE_AGENT);
      unsigned long long hi = __hip_atomic_load(
          hbase + idx + 1, __ATOMIC_RELAXED, __HIP_MEMORY_SCOPE_AGENT);
      ull2 u;
      u[0] = lo;
      u[1] = hi;
      hf[kk] = __builtin_bit_cast(bf16x8, u);
    }

    // x-proj second half: hides h-load L3 latency
#pragma unroll
    for (int kk = 4; kk < 8; kk++) {
      bf16x8 a = xr[kk * 4 + q];
      aX0 = __builtin_amdgcn_mfma_f32_16x16x32_bf16(a, wi[0][kk], aX0, 0, 0, 0);
      aX1 = __builtin_amdgcn_mfma_f32_16x16x32_bf16(a, wi[1][kk], aX1, 0, 0, 0);
    }

    // h-projection
#pragma unroll
    for (int kk = 0; kk < 16; kk++) {
      aH0 = __builtin_amdgcn_mfma_f32_16x16x32_bf16(hf[kk], wh[0][kk], aH0, 0, 0, 0);
      aH1 = __builtin_amdgcn_mfma_f32_16x16x32_bf16(hf[kk], wh[1][kk], aH1, 0, 0, 0);
    }

    // epilogue: C/D layout col=lane&15, row=q*4+reg. Lane c<8 owns col wg*8+c.
#pragma unroll
    for (int r = 0; r < 4; r++) {
      float xz = __shfl_xor(aX0[r], 8, 64);
      float hz = __shfl_xor(aH0[r], 8, 64);
      float rr = sigm(aX0[r] + bri + aH0[r] + brh);
      float zz = sigm(xz + bzi + hz + bzh);
      float nn = tanh_f(aX1[r] + bni + rr * (aH1[r] + bnh));
      float hv = (1.0f - zz) * nn + zz * hold[r];
      hold[r] = hv;
      if (c < 8) trans[wave][q * 4 + r][c] = (unsigned short)f2b(hv);
    }

    if (t < NT - 1) {
      // per-wave LDS transpose -> coalesced contiguous stores. LDS pipeline
      // is in-order per wave; lgkmcnt(0) + memory clobber orders write->read.
      asm volatile("s_waitcnt lgkmcnt(0)" ::: "memory");
      if (lane < 16) {
        int b = wave * 16 + lane;
        const unsigned long long* tp =
            (const unsigned long long*)&trans[wave][lane][0];
        unsigned long long v0 = tp[0], v1 = tp[1];
        unsigned long long* dst =
            (unsigned long long*)(hnext + ((size_t)wg * 64 + b) * 8);
        __hip_atomic_store(dst, v0, __ATOMIC_RELAXED, __HIP_MEMORY_SCOPE_AGENT);
        __hip_atomic_store(dst + 1, v1, __ATOMIC_RELAXED,
                           __HIP_MEMORY_SCOPE_AGENT);
      }
      // stores (and this step's h loads) complete at coherency point ...
      asm volatile("s_waitcnt vmcnt(0)" ::: "memory");
      // ... then signal: LDS-aggregate arrivals, last wave does ONE global add
      if (lane == 0) {
        int old = __hip_atomic_fetch_add(&lds_cnt, 1, __ATOMIC_RELAXED,
                                         __HIP_MEMORY_SCOPE_WORKGROUP);
        if ((old & 3) == 3)
          __hip_atomic_fetch_add(&cnt[t], 1, __ATOMIC_RELAXED,
                                 __HIP_MEMORY_SCOPE_AGENT);
      }
    }
  }

  // final h (fp32 master copy) -> d_out
  if (c < 8) {
#pragma unroll
    for (int r = 0; r < 4; r++) {
      int b = wave * 16 + q * 4 + r;
      out[(size_t)b * NH + wg * 8 + c] = hold[r];
    }
  }
}

extern "C" void kernel_launch(void* const* d_in, const int* in_sizes, int n_in,
                              void* d_out, int out_size, void* d_ws, size_t ws_size,
                              hipStream_t stream) {
  const float* x   = (const float*)d_in[0];
  const float* Wih = (const float*)d_in[1];
  const float* Whh = (const float*)d_in[2];
  const float* bih = (const float*)d_in[3];
  const float* bhh = (const float*)d_in[4];
  float* out = (float*)d_out;
  hipLaunchKernelGGL(gru_persistent, dim3(NB), dim3(256), 0, stream,
                     x, Wih, Whh, bih, bhh, out, (unsigned char*)d_ws);
}

// Round 4
// 2662.565 us; speedup vs baseline: 1.8378x; 1.0700x over previous
//
#include <hip/hip_runtime.h>
#include <hip/hip_bf16.h>

// GRU last-hidden: B=64, T=512, I=256, H=512, fp32 in/out.
// Persistent kernel: 64 WGs x 256 thr. WG w owns h-cols [8w,8w+8) for ALL
// batches; weights live in VGPR MFMA B-fragments for the whole kernel.
//
// Round-4 structure: FOUR INDEPENDENT WAVE PIPELINES with distributed tags.
// Wave u of every WG handles batches [16u,16u+16). Consumer wave u reads,
// from each producer WG w', exactly the 256B block written by wave u of w'.
// So sync is per-(wave,WG) tag: producer wave stores its data block, waits
// vmcnt(0) (data at coherency point), then stores tags[u][w] = t+2 (plain
// store, NO atomics/RMW). Consumer wave u: lane l polls tags[u][l], exits on
// __all(v >= t+1). No central counter, no LDS aggregation, no __syncthreads
// in the loop. All cross-WG traffic via relaxed agent-scope accesses
// (write-through past per-XCD L2; loads read L3 directly). Tags monotone
// (no reset, no ABA); 0xAA ws poison reads as negative int -> safe.

#define NB 64
#define NT 512
#define NI 256
#define NH 512

typedef __attribute__((ext_vector_type(8))) short bf16x8;
typedef __attribute__((ext_vector_type(4))) float f32x4;
typedef __attribute__((ext_vector_type(2))) unsigned long long ull2;

static __device__ __forceinline__ short f2b(float f) {
  unsigned u = __builtin_bit_cast(unsigned, f);
  unsigned r = (u + 0x7fffu + ((u >> 16) & 1u)) >> 16;
  return (short)r;
}
static __device__ __forceinline__ float sigm(float x) {
  return 1.0f / (1.0f + __expf(-x));
}
static __device__ __forceinline__ float tanh_f(float x) {
  return 1.0f - 2.0f / (__expf(2.0f * x) + 1.0f);
}

__global__ __launch_bounds__(256, 1)
void gru_persistent(const float* __restrict__ x,
                    const float* __restrict__ Wih,
                    const float* __restrict__ Whh,
                    const float* __restrict__ bih,
                    const float* __restrict__ bhh,
                    float* __restrict__ out,
                    unsigned char* __restrict__ ws) {
  const int wg   = blockIdx.x;    // 0..63 : owns h-cols [8wg, 8wg+8)
  const int tid  = threadIdx.x;   // 0..255
  const int wave = tid >> 6;      // 0..3  : owns batches [16*wave, 16*wave+16)
  const int lane = tid & 63;
  const int c    = lane & 15;     // tile col / A-row index
  const int q    = lane >> 4;     // quad: k-group (A/B), row-group (C/D)

  // ws layout: [0,8K) init-barrier slots; [8K,9K) tags[4][64] (int);
  // h_ex bufs at 16K and 16K+64K (each: [64 wg][64 b][8 cols] bf16 = 64KB);
  // xb (x as bf16, [b][t][i]) at 16K+128K.
  int* slots = (int*)ws;
  int* tags  = (int*)(ws + 8192);
  unsigned short* hb0 = (unsigned short*)(ws + 16384);
  unsigned short* hb1 = (unsigned short*)(ws + 16384 + 65536);
  unsigned short* xb  = (unsigned short*)(ws + 16384 + 2 * 65536);

  __shared__ unsigned short trans[4][16][8];  // per-wave transpose bounce

  // ---- prologue: x fp32->bf16, zero h0 and tags ----
  {
    const float4* x4 = (const float4*)x;
    const int total4 = NB * NT * NI / 4;
    const int nthr = NB * 256;
    for (int i = wg * 256 + tid; i < total4; i += nthr) {
      float4 v = x4[i];
      ushort4 o;
      o.x = (unsigned short)f2b(v.x);
      o.y = (unsigned short)f2b(v.y);
      o.z = (unsigned short)f2b(v.z);
      o.w = (unsigned short)f2b(v.w);
      ((ushort4*)xb)[i] = o;
    }
    ((unsigned int*)hb0)[wg * 256 + tid] = 0u;  // h0 = 0 (64KB total)
    if (wg == 0) tags[tid] = 0;                 // 256 tags
  }

  // ---- loop-invariant weight fragments into registers ----
  bf16x8 wh[2][16];  // W_hh, K=512 -> 16 k-steps
  bf16x8 wi[2][8];   // W_ih, K=256 -> 8 k-steps
#pragma unroll
  for (int nt = 0; nt < 2; nt++) {
    int nl = nt * 16 + c;
    bool valid = nl < 24;
    int gate = nl >> 3;
    int jj = nl & 7;
    int grow = valid ? (gate * NH + wg * 8 + jj) : 0;
#pragma unroll
    for (int kk = 0; kk < 16; kk++) {
      const float* p = Whh + (size_t)grow * NH + kk * 32 + q * 8;
      bf16x8 f;
#pragma unroll
      for (int e = 0; e < 8; e++) f[e] = valid ? f2b(p[e]) : (short)0;
      wh[nt][kk] = f;
    }
#pragma unroll
    for (int kk = 0; kk < 8; kk++) {
      const float* p = Wih + (size_t)grow * NI + kk * 32 + q * 8;
      bf16x8 f;
#pragma unroll
      for (int e = 0; e < 8; e++) f[e] = valid ? f2b(p[e]) : (short)0;
      wi[nt][kk] = f;
    }
  }

  const int jcol = wg * 8 + (c & 7);
  const float bri = bih[jcol],          brh = bhh[jcol];
  const float bzi = bih[NH + jcol],     bzh = bhh[NH + jcol];
  const float bni = bih[2 * NH + jcol], bnh = bhh[2 * NH + jcol];

  float hold[4] = {0.f, 0.f, 0.f, 0.f};  // fp32 master state (c<8 lanes)

  // ---- one-time init barrier: xb, h0, tag zeros visible device-wide ----
  // (release store -> L2 writeback; threadfence after poll -> invalidate).
  // Only cache-maintenance in the kernel.
  __syncthreads();
  if (tid == 0)
    __hip_atomic_store(&slots[wg * 32], 1, __ATOMIC_RELEASE,
                       __HIP_MEMORY_SCOPE_AGENT);
  if (wave == 0) {
    while (__hip_atomic_load(&slots[lane * 32], __ATOMIC_RELAXED,
                             __HIP_MEMORY_SCOPE_AGENT) < 1)
      __builtin_amdgcn_s_sleep(1);
  }
  __syncthreads();
  __threadfence();

  const int b0 = wave * 16 + c;       // A-fragment batch row for this lane
  int* mytags = tags + wave * 64;     // this wave-group's 64 tags

  for (int t = 0; t < NT; t++) {
    const unsigned short* hcur = (t & 1) ? hb1 : hb0;
    unsigned short* hnext      = (t & 1) ? hb0 : hb1;

    f32x4 aX0 = {0.f, 0.f, 0.f, 0.f}, aX1 = {0.f, 0.f, 0.f, 0.f};
    f32x4 aH0 = {0.f, 0.f, 0.f, 0.f}, aH1 = {0.f, 0.f, 0.f, 0.f};

    const bf16x8* xr = (const bf16x8*)(xb + ((size_t)b0 * NT + t) * NI);

    // x-proj first half (cached loads; fills time before readiness)
#pragma unroll
    for (int kk = 0; kk < 4; kk++) {
      bf16x8 a = xr[kk * 4 + q];
      aX0 = __builtin_amdgcn_mfma_f32_16x16x32_bf16(a, wi[0][kk], aX0, 0, 0, 0);
      aX1 = __builtin_amdgcn_mfma_f32_16x16x32_bf16(a, wi[1][kk], aX1, 0, 0, 0);
    }

    // wait for h_t from this wave-group's 64 producers: lane l polls
    // tags[wave][l] (2 lines per group; pure reads, no RMW anywhere)
    if (t > 0) {
      const int need = t + 1;
      while (true) {
        int v = __hip_atomic_load(&mytags[lane], __ATOMIC_RELAXED,
                                  __HIP_MEMORY_SCOPE_AGENT);
        if (__all(v >= need)) break;
      }
      asm volatile("" ::: "memory");  // compiler barrier only
    }

    // h fragment loads: h_ex[wg'=kk*4+q][b0][0..8) -> contiguous 16B pair;
    // 16 lanes (consecutive b0) form 256B coalesced chunks.
    const unsigned long long* hbase = (const unsigned long long*)hcur;
    bf16x8 hf[16];
#pragma unroll
    for (int kk = 0; kk < 16; kk++) {
      size_t idx = ((size_t)(kk * 4 + q) * 64 + b0) * 2;
      unsigned long long lo = __hip_atomic_load(
          hbase + idx, __ATOMIC_RELAXED, __HIP_MEMORY_SCOPE_AGENT);
      unsigned long long hi = __hip_atomic_load(
          hbase + idx + 1, __ATOMIC_RELAXED, __HIP_MEMORY_SCOPE_AGENT);
      ull2 u;
      u[0] = lo;
      u[1] = hi;
      hf[kk] = __builtin_bit_cast(bf16x8, u);
    }

    // x-proj second half: hides h-load L3 latency
#pragma unroll
    for (int kk = 4; kk < 8; kk++) {
      bf16x8 a = xr[kk * 4 + q];
      aX0 = __builtin_amdgcn_mfma_f32_16x16x32_bf16(a, wi[0][kk], aX0, 0, 0, 0);
      aX1 = __builtin_amdgcn_mfma_f32_16x16x32_bf16(a, wi[1][kk], aX1, 0, 0, 0);
    }

    // h-projection
#pragma unroll
    for (int kk = 0; kk < 16; kk++) {
      aH0 = __builtin_amdgcn_mfma_f32_16x16x32_bf16(hf[kk], wh[0][kk], aH0, 0, 0, 0);
      aH1 = __builtin_amdgcn_mfma_f32_16x16x32_bf16(hf[kk], wh[1][kk], aH1, 0, 0, 0);
    }

    // epilogue: C/D layout col=lane&15, row=q*4+reg. Lane c<8 owns col wg*8+c.
#pragma unroll
    for (int r = 0; r < 4; r++) {
      float xz = __shfl_xor(aX0[r], 8, 64);
      float hz = __shfl_xor(aH0[r], 8, 64);
      float rr = sigm(aX0[r] + bri + aH0[r] + brh);
      float zz = sigm(xz + bzi + hz + bzh);
      float nn = tanh_f(aX1[r] + bni + rr * (aH1[r] + bnh));
      float hv = (1.0f - zz) * nn + zz * hold[r];
      hold[r] = hv;
      if (c < 8) trans[wave][q * 4 + r][c] = (unsigned short)f2b(hv);
    }

    if (t < NT - 1) {
      // per-wave LDS transpose -> coalesced 8B stores (LDS in-order per wave)
      asm volatile("s_waitcnt lgkmcnt(0)" ::: "memory");
      if (lane < 16) {
        int b = wave * 16 + lane;
        const unsigned long long* tp =
            (const unsigned long long*)&trans[wave][lane][0];
        unsigned long long v0 = tp[0], v1 = tp[1];
        unsigned long long* dst =
            (unsigned long long*)(hnext + ((size_t)wg * 64 + b) * 8);
        __hip_atomic_store(dst, v0, __ATOMIC_RELAXED, __HIP_MEMORY_SCOPE_AGENT);
        __hip_atomic_store(dst + 1, v1, __ATOMIC_RELAXED,
                           __HIP_MEMORY_SCOPE_AGENT);
      }
      // data stores (and this wave's step-t h loads) at coherency point ...
      asm volatile("s_waitcnt vmcnt(0)" ::: "memory");
      // ... then publish this wave's tag (plain store, monotone value)
      if (lane == 0)
        __hip_atomic_store(&mytags[wg], t + 2, __ATOMIC_RELAXED,
                           __HIP_MEMORY_SCOPE_AGENT);
    }
  }

  // final h (fp32 master copy) -> d_out
  if (c < 8) {
#pragma unroll
    for (int r = 0; r < 4; r++) {
      int b = wave * 16 + q * 4 + r;
      out[(size_t)b * NH + wg * 8 + c] = hold[r];
    }
  }
}

extern "C" void kernel_launch(void* const* d_in, const int* in_sizes, int n_in,
                              void* d_out, int out_size, void* d_ws, size_t ws_size,
                              hipStream_t stream) {
  const float* x   = (const float*)d_in[0];
  const float* Wih = (const float*)d_in[1];
  const float* Whh = (const float*)d_in[2];
  const float* bih = (const float*)d_in[3];
  const float* bhh = (const float*)d_in[4];
  float* out = (float*)d_out;
  hipLaunchKernelGGL(gru_persistent, dim3(NB), dim3(256), 0, stream,
                     x, Wih, Whh, bih, bhh, out, (unsigned char*)d_ws);
}

// Round 5
// 1828.656 us; speedup vs baseline: 2.6759x; 1.4560x over previous
//
#include <hip/hip_runtime.h>
#include <hip/hip_bf16.h>

// GRU last-hidden: B=64, T=512, I=256, H=512, fp32 in/out.
// Persistent kernel: 64 WGs x 256 thr. WG w owns h-cols [8w,8w+8) for ALL
// batches; weights live in VGPR MFMA B-fragments for the whole kernel.
//
// Round-5 change: COALESCED device-coherent h loads. R2-R4 moved h with
// per-lane ATOMIC loads, which do not coalesce: 32 instr x 64 lanes = 2048
// L3 transactions per wave per step (x4 waves per CU TA port) — the ~5 us/
// step floor. Now the 16 h-fragment loads are plain global_load_dwordx4
// with sc1 (agent-coherent: bypass L1/L2, read L3 fresh) via inline asm —
// 8 line transactions per instr — issued as one burst with a single
// explicit s_waitcnt vmcnt(0). Tag poll likewise one coalesced dword load.
// Producer side keeps the proven 8B-atomic stores (32 transactions/wave,
// negligible) + vmcnt(0) + tag store; protocol identical to R4 (monotone
// per-(wave,WG) tags certify data-at-L3 AND prior-step reads drained).

#define NB 64
#define NT 512
#define NI 256
#define NH 512

typedef __attribute__((ext_vector_type(8))) short bf16x8;
typedef __attribute__((ext_vector_type(4))) float f32x4;
typedef __attribute__((ext_vector_type(4))) int i32x4;

static __device__ __forceinline__ short f2b(float f) {
  unsigned u = __builtin_bit_cast(unsigned, f);
  unsigned r = (u + 0x7fffu + ((u >> 16) & 1u)) >> 16;
  return (short)r;
}
static __device__ __forceinline__ float sigm(float x) {
  return 1.0f / (1.0f + __expf(-x));
}
static __device__ __forceinline__ float tanh_f(float x) {
  return 1.0f - 2.0f / (__expf(2.0f * x) + 1.0f);
}

__global__ __launch_bounds__(256, 1)
void gru_persistent(const float* __restrict__ x,
                    const float* __restrict__ Wih,
                    const float* __restrict__ Whh,
                    const float* __restrict__ bih,
                    const float* __restrict__ bhh,
                    float* __restrict__ out,
                    unsigned char* __restrict__ ws) {
  const int wg   = blockIdx.x;    // 0..63 : owns h-cols [8wg, 8wg+8)
  const int tid  = threadIdx.x;   // 0..255
  const int wave = tid >> 6;      // 0..3  : owns batches [16*wave, 16*wave+16)
  const int lane = tid & 63;
  const int c    = lane & 15;     // tile col / A-row index
  const int q    = lane >> 4;     // quad: k-group (A/B), row-group (C/D)

  // ws layout: [0,8K) init-barrier slots; [8K,9K) tags[4][64] (int);
  // h_ex bufs at 16K and 16K+64K ([64 wg][64 b][8 cols] bf16 = 64KB each);
  // xb (x as bf16, [b][t][i]) at 16K+128K.
  int* slots = (int*)ws;
  int* tags  = (int*)(ws + 8192);
  unsigned short* hb0 = (unsigned short*)(ws + 16384);
  unsigned short* hb1 = (unsigned short*)(ws + 16384 + 65536);
  unsigned short* xb  = (unsigned short*)(ws + 16384 + 2 * 65536);

  __shared__ unsigned short trans[4][16][8];  // per-wave transpose bounce

  // ---- prologue: x fp32->bf16, zero h0 and tags ----
  {
    const float4* x4 = (const float4*)x;
    const int total4 = NB * NT * NI / 4;
    const int nthr = NB * 256;
    for (int i = wg * 256 + tid; i < total4; i += nthr) {
      float4 v = x4[i];
      ushort4 o;
      o.x = (unsigned short)f2b(v.x);
      o.y = (unsigned short)f2b(v.y);
      o.z = (unsigned short)f2b(v.z);
      o.w = (unsigned short)f2b(v.w);
      ((ushort4*)xb)[i] = o;
    }
    ((unsigned int*)hb0)[wg * 256 + tid] = 0u;  // h0 = 0 (64KB total)
    if (wg == 0) tags[tid] = 0;                 // 256 tags
  }

  // ---- loop-invariant weight fragments into registers ----
  bf16x8 wh[2][16];  // W_hh, K=512 -> 16 k-steps
  bf16x8 wi[2][8];   // W_ih, K=256 -> 8 k-steps
#pragma unroll
  for (int nt = 0; nt < 2; nt++) {
    int nl = nt * 16 + c;
    bool valid = nl < 24;
    int gate = nl >> 3;
    int jj = nl & 7;
    int grow = valid ? (gate * NH + wg * 8 + jj) : 0;
#pragma unroll
    for (int kk = 0; kk < 16; kk++) {
      const float* p = Whh + (size_t)grow * NH + kk * 32 + q * 8;
      bf16x8 f;
#pragma unroll
      for (int e = 0; e < 8; e++) f[e] = valid ? f2b(p[e]) : (short)0;
      wh[nt][kk] = f;
    }
#pragma unroll
    for (int kk = 0; kk < 8; kk++) {
      const float* p = Wih + (size_t)grow * NI + kk * 32 + q * 8;
      bf16x8 f;
#pragma unroll
      for (int e = 0; e < 8; e++) f[e] = valid ? f2b(p[e]) : (short)0;
      wi[nt][kk] = f;
    }
  }

  const int jcol = wg * 8 + (c & 7);
  const float bri = bih[jcol],          brh = bhh[jcol];
  const float bzi = bih[NH + jcol],     bzh = bhh[NH + jcol];
  const float bni = bih[2 * NH + jcol], bnh = bhh[2 * NH + jcol];

  float hold[4] = {0.f, 0.f, 0.f, 0.f};  // fp32 master state (c<8 lanes)

  // ---- one-time init barrier: xb, h0, tag zeros visible device-wide ----
  // (release store -> L2 writeback; threadfence after poll -> invalidate).
  __syncthreads();
  if (tid == 0)
    __hip_atomic_store(&slots[wg * 32], 1, __ATOMIC_RELEASE,
                       __HIP_MEMORY_SCOPE_AGENT);
  if (wave == 0) {
    while (__hip_atomic_load(&slots[lane * 32], __ATOMIC_RELAXED,
                             __HIP_MEMORY_SCOPE_AGENT) < 1)
      __builtin_amdgcn_s_sleep(1);
  }
  __syncthreads();
  __threadfence();

  const int b0 = wave * 16 + c;       // A-fragment batch row for this lane
  int* mytags = tags + wave * 64;     // this wave-group's 64 tags
  const int* tagp = mytags + lane;    // per-lane poll address (coalesced)

  for (int t = 0; t < NT; t++) {
    const unsigned short* hcur = (t & 1) ? hb1 : hb0;
    unsigned short* hnext      = (t & 1) ? hb0 : hb1;

    f32x4 aX0 = {0.f, 0.f, 0.f, 0.f}, aX1 = {0.f, 0.f, 0.f, 0.f};
    f32x4 aH0 = {0.f, 0.f, 0.f, 0.f}, aH1 = {0.f, 0.f, 0.f, 0.f};

    const bf16x8* xr = (const bf16x8*)(xb + ((size_t)b0 * NT + t) * NI);

    // x-projection (cached loads; fills the wall-clock while producers
    // publish). Fully before the poll.
#pragma unroll
    for (int kk = 0; kk < 8; kk++) {
      bf16x8 a = xr[kk * 4 + q];
      aX0 = __builtin_amdgcn_mfma_f32_16x16x32_bf16(a, wi[0][kk], aX0, 0, 0, 0);
      aX1 = __builtin_amdgcn_mfma_f32_16x16x32_bf16(a, wi[1][kk], aX1, 0, 0, 0);
    }

    // wait for h_t from this wave-group's 64 producers: ONE coalesced
    // agent-coherent dword load per iteration (2 line transactions).
    if (t > 0) {
      const int need = t + 1;
      while (true) {
        int v;
        asm volatile("global_load_dword %0, %1, off sc1"
                     : "=v"(v) : "v"(tagp));
        asm volatile("s_waitcnt vmcnt(0)" : "+v"(v)::"memory");
        if (__all(v >= need)) break;
      }
    }

    // h fragment burst: 16 coalesced 16B agent-coherent loads, issued
    // up-front (compiler-opaque volatile asm cannot sink them), then one
    // explicit wait with register deps.
    i32x4 hv[16];
    {
      const char* hb = (const char*)hcur;
#pragma unroll
      for (int kk = 0; kk < 16; kk++) {
        const void* ap = hb + (size_t)(((kk * 4 + q) * 64 + b0) << 4);
        asm volatile("global_load_dwordx4 %0, %1, off sc1"
                     : "=v"(hv[kk]) : "v"(ap));
      }
      asm volatile("s_waitcnt vmcnt(0)"
                   : "+v"(hv[0]), "+v"(hv[1]), "+v"(hv[2]), "+v"(hv[3]),
                     "+v"(hv[4]), "+v"(hv[5]), "+v"(hv[6]), "+v"(hv[7]),
                     "+v"(hv[8]), "+v"(hv[9]), "+v"(hv[10]), "+v"(hv[11]),
                     "+v"(hv[12]), "+v"(hv[13]), "+v"(hv[14]), "+v"(hv[15])
                   ::"memory");
    }

    // h-projection
#pragma unroll
    for (int kk = 0; kk < 16; kk++) {
      bf16x8 a = __builtin_bit_cast(bf16x8, hv[kk]);
      aH0 = __builtin_amdgcn_mfma_f32_16x16x32_bf16(a, wh[0][kk], aH0, 0, 0, 0);
      aH1 = __builtin_amdgcn_mfma_f32_16x16x32_bf16(a, wh[1][kk], aH1, 0, 0, 0);
    }

    // epilogue: C/D layout col=lane&15, row=q*4+reg. Lane c<8 owns col wg*8+c.
#pragma unroll
    for (int r = 0; r < 4; r++) {
      float xz = __shfl_xor(aX0[r], 8, 64);
      float hz = __shfl_xor(aH0[r], 8, 64);
      float rr = sigm(aX0[r] + bri + aH0[r] + brh);
      float zz = sigm(xz + bzi + hz + bzh);
      float nn = tanh_f(aX1[r] + bni + rr * (aH1[r] + bnh));
      float hv2 = (1.0f - zz) * nn + zz * hold[r];
      hold[r] = hv2;
      if (c < 8) trans[wave][q * 4 + r][c] = (unsigned short)f2b(hv2);
    }

    if (t < NT - 1) {
      // per-wave LDS transpose -> coalesced 8B stores (LDS in-order per wave)
      asm volatile("s_waitcnt lgkmcnt(0)" ::: "memory");
      if (lane < 16) {
        int b = wave * 16 + lane;
        const unsigned long long* tp =
            (const unsigned long long*)&trans[wave][lane][0];
        unsigned long long v0 = tp[0], v1 = tp[1];
        unsigned long long* dst =
            (unsigned long long*)(hnext + ((size_t)wg * 64 + b) * 8);
        __hip_atomic_store(dst, v0, __ATOMIC_RELAXED, __HIP_MEMORY_SCOPE_AGENT);
        __hip_atomic_store(dst + 1, v1, __ATOMIC_RELAXED,
                           __HIP_MEMORY_SCOPE_AGENT);
      }
      // data stores (and this wave's step-t h loads) at coherency point ...
      asm volatile("s_waitcnt vmcnt(0)" ::: "memory");
      // ... then publish this wave's tag (plain store, monotone value)
      if (lane == 0)
        __hip_atomic_store(&mytags[wg], t + 2, __ATOMIC_RELAXED,
                           __HIP_MEMORY_SCOPE_AGENT);
    }
  }

  // final h (fp32 master copy) -> d_out
  if (c < 8) {
#pragma unroll
    for (int r = 0; r < 4; r++) {
      int b = wave * 16 + q * 4 + r;
      out[(size_t)b * NH + wg * 8 + c] = hold[r];
    }
  }
}

extern "C" void kernel_launch(void* const* d_in, const int* in_sizes, int n_in,
                              void* d_out, int out_size, void* d_ws, size_t ws_size,
                              hipStream_t stream) {
  const float* x   = (const float*)d_in[0];
  const float* Wih = (const float*)d_in[1];
  const float* Whh = (const float*)d_in[2];
  const float* bih = (const float*)d_in[3];
  const float* bhh = (const float*)d_in[4];
  float* out = (float*)d_out;
  hipLaunchKernelGGL(gru_persistent, dim3(NB), dim3(256), 0, stream,
                     x, Wih, Whh, bih, bhh, out, (unsigned char*)d_ws);
}